// Round 4
// baseline (552.488 us; speedup 1.0000x reference)
//
#include <hip/hip_runtime.h>

#define IN_F 128
#define HID 256
#define HID2 128

#define BK 32
#define BN 128

// ---------------- CSR build ----------------
__global__ void count_deg(const int* __restrict__ col, int* __restrict__ deg, int E) {
    int e = blockIdx.x * blockDim.x + threadIdx.x;
    if (e < E) atomicAdd(&deg[col[e]], 1);
}

// 3-phase parallel exclusive scan
__global__ __launch_bounds__(256) void scan_block(const int* __restrict__ deg,
                                                  int* __restrict__ tmp,
                                                  int* __restrict__ bsum, int n) {
    int b = blockIdx.x, t = threadIdx.x, i = b * 256 + t;
    int lane = t & 63, w = t >> 6;
    int v = (i < n) ? deg[i] : 0;
    int x = v;
#pragma unroll
    for (int d = 1; d < 64; d <<= 1) {
        int y = __shfl_up(x, d, 64);
        if (lane >= d) x += y;
    }
    __shared__ int ws[4];
    if (lane == 63) ws[w] = x;
    __syncthreads();
    if (t < 4) {
        int s = ws[t];
#pragma unroll
        for (int d = 1; d < 4; d <<= 1) {
            int y = __shfl_up(s, d, 64);
            if (t >= d) s += y;
        }
        ws[t] = s;
    }
    __syncthreads();
    x += (w ? ws[w - 1] : 0);
    if (i < n) tmp[i] = x;
    if (t == 255) bsum[b] = x;
}

__global__ __launch_bounds__(256) void scan_bsums(int* __restrict__ bsum, int nb) {
    int t = threadIdx.x, lane = t & 63, w = t >> 6;
    int v = (t < nb) ? bsum[t] : 0;
    int x = v;
#pragma unroll
    for (int d = 1; d < 64; d <<= 1) {
        int y = __shfl_up(x, d, 64);
        if (lane >= d) x += y;
    }
    __shared__ int ws[4];
    if (lane == 63) ws[w] = x;
    __syncthreads();
    if (t < 4) {
        int s = ws[t];
#pragma unroll
        for (int d = 1; d < 4; d <<= 1) {
            int y = __shfl_up(s, d, 64);
            if (t >= d) s += y;
        }
        ws[t] = s;
    }
    __syncthreads();
    x += (w ? ws[w - 1] : 0);
    if (t < nb) bsum[t] = x;
}

__global__ void scan_add(const int* __restrict__ tmp, const int* __restrict__ bsum,
                         int* __restrict__ rp, int n) {
    int b = blockIdx.x, i = b * 256 + threadIdx.x;
    if (i < n) {
        rp[i + 1] = tmp[i] + (b ? bsum[b - 1] : 0);
        if (i == 0) rp[0] = 0;
    }
}

__global__ void fill_csr(const int* __restrict__ row, const int* __restrict__ col,
                         const int* __restrict__ rp, int* __restrict__ fill,
                         int* __restrict__ csr, int E) {
    int e = blockIdx.x * blockDim.x + threadIdx.x;
    if (e < E) {
        int c = col[e];
        int p = atomicAdd(&fill[c], 1);
        csr[rp[c] + p] = row[e];
    }
}

// ------- aggregation: wave-per-node, float2/lane, 4-edge unroll for MLP -------
__global__ __launch_bounds__(256) void agg_gather(const float* __restrict__ x,
                                                  const int* __restrict__ rp,
                                                  const int* __restrict__ csr,
                                                  float* __restrict__ out, int N) {
    int w = threadIdx.x >> 6, lane = threadIdx.x & 63;
    int n = blockIdx.x * 4 + w;
    if (n >= N) return;
    int s = rp[n], e = rp[n + 1];
    const float2* x2 = (const float2*)x;
    float2 a0 = {0.f, 0.f}, a1 = {0.f, 0.f}, a2 = {0.f, 0.f}, a3 = {0.f, 0.f};
    int i = s;
    for (; i + 3 < e; i += 4) {
        int s0 = csr[i], s1 = csr[i + 1], s2 = csr[i + 2], s3 = csr[i + 3];
        float2 v0 = x2[(size_t)s0 * 64 + lane];
        float2 v1 = x2[(size_t)s1 * 64 + lane];
        float2 v2 = x2[(size_t)s2 * 64 + lane];
        float2 v3 = x2[(size_t)s3 * 64 + lane];
        a0.x += v0.x; a0.y += v0.y; a1.x += v1.x; a1.y += v1.y;
        a2.x += v2.x; a2.y += v2.y; a3.x += v3.x; a3.y += v3.y;
    }
    for (; i < e; i++) {
        float2 v = x2[(size_t)csr[i] * 64 + lane];
        a0.x += v.x; a0.y += v.y;
    }
    float dinv = 1.f / fmaxf((float)(e - s), 1.f);
    float2* o2 = (float2*)out;
    o2[(size_t)n * 64 + lane] = make_float2((a0.x + a1.x + a2.x + a3.x) * dinv,
                                            (a0.y + a1.y + a2.y + a3.y) * dinv);
}

// ---------------- GEMM: C[M,N] = A[M,K] @ W[N,K]^T (+bias,relu) ----------------
// 256 threads as 16x16 grid; micro-tile MT x 8 (MT=8: BM=128; MT=4: BM=64), BN=128.
// k-major transposed LDS tiles. Per k-step: MT*8 FMAs per (MT+8)*4 B LDS read;
// a-reads are 4-unique-address (broadcast, conflict-free), w-reads 16-unique
// (4-way ~1.58x, non-binding). Register prefetch of next K-chunk overlaps compute.
template<int MT, bool RELU_BIAS>
__global__ __launch_bounds__(256, 3) void gemm_t8(const float* __restrict__ A,
                                                  const float* __restrict__ W,
                                                  const float* __restrict__ bias,
                                                  float* __restrict__ C,
                                                  int M, int N, int K) {
    constexpr int BM = 16 * MT;
    constexpr int NA4 = BM / 32;            // float4 per thread for A-tile (BM*32/4/256)
    __shared__ float As[BK][BM + 4];
    __shared__ float Ws[BK][BN + 4];
    int m0 = blockIdx.x * BM, n0 = blockIdx.y * BN;
    int t = threadIdx.x;
    int tr = t >> 4, tc = t & 15;           // rows m0+MT*tr+i, cols n0+8*tc+j

    int am[NA4], ak4[NA4];
#pragma unroll
    for (int it = 0; it < NA4; it++) { int id = t + 256 * it; am[it] = id >> 3; ak4[it] = id & 7; }
    int wn[4], wk4[4];
#pragma unroll
    for (int it = 0; it < 4; it++) { int id = t + 256 * it; wn[it] = id >> 3; wk4[it] = id & 7; }

    float4 av[NA4], wv[4];
    auto load_chunk = [&](int kc) {
#pragma unroll
        for (int it = 0; it < NA4; it++) {
            int m = m0 + am[it];
            av[it] = (m < M) ? *(const float4*)&A[(size_t)m * K + kc + 4 * ak4[it]]
                             : make_float4(0.f, 0.f, 0.f, 0.f);
        }
#pragma unroll
        for (int it = 0; it < 4; it++)
            wv[it] = *(const float4*)&W[(size_t)(n0 + wn[it]) * K + kc + 4 * wk4[it]];
    };

    load_chunk(0);
    float acc[MT][8];
#pragma unroll
    for (int i = 0; i < MT; i++)
#pragma unroll
        for (int j = 0; j < 8; j++) acc[i][j] = 0.f;

    for (int kc = 0; kc < K; kc += BK) {
        __syncthreads();
#pragma unroll
        for (int it = 0; it < NA4; it++) {
            As[4 * ak4[it] + 0][am[it]] = av[it].x;
            As[4 * ak4[it] + 1][am[it]] = av[it].y;
            As[4 * ak4[it] + 2][am[it]] = av[it].z;
            As[4 * ak4[it] + 3][am[it]] = av[it].w;
        }
#pragma unroll
        for (int it = 0; it < 4; it++) {
            Ws[4 * wk4[it] + 0][wn[it]] = wv[it].x;
            Ws[4 * wk4[it] + 1][wn[it]] = wv[it].y;
            Ws[4 * wk4[it] + 2][wn[it]] = wv[it].z;
            Ws[4 * wk4[it] + 3][wn[it]] = wv[it].w;
        }
        __syncthreads();
        if (kc + BK < K) load_chunk(kc + BK);
#pragma unroll
        for (int k = 0; k < BK; k++) {
            float4 w0 = *(const float4*)&Ws[k][8 * tc];
            float4 w1 = *(const float4*)&Ws[k][8 * tc + 4];
            float a[MT];
#pragma unroll
            for (int h = 0; h < MT / 4; h++) {
                float4 aq = *(const float4*)&As[k][MT * tr + 4 * h];
                a[4 * h] = aq.x; a[4 * h + 1] = aq.y; a[4 * h + 2] = aq.z; a[4 * h + 3] = aq.w;
            }
#pragma unroll
            for (int i = 0; i < MT; i++) {
                acc[i][0] += a[i] * w0.x; acc[i][1] += a[i] * w0.y;
                acc[i][2] += a[i] * w0.z; acc[i][3] += a[i] * w0.w;
                acc[i][4] += a[i] * w1.x; acc[i][5] += a[i] * w1.y;
                acc[i][6] += a[i] * w1.z; acc[i][7] += a[i] * w1.w;
            }
        }
    }

    float4 b0 = make_float4(0.f, 0.f, 0.f, 0.f), b1 = b0;
    if (RELU_BIAS) {
        b0 = *(const float4*)&bias[n0 + 8 * tc];
        b1 = *(const float4*)&bias[n0 + 8 * tc + 4];
    }
#pragma unroll
    for (int i = 0; i < MT; i++) {
        int m = m0 + MT * tr + i;
        if (m < M) {
            float4 v0 = make_float4(acc[i][0], acc[i][1], acc[i][2], acc[i][3]);
            float4 v1 = make_float4(acc[i][4], acc[i][5], acc[i][6], acc[i][7]);
            if (RELU_BIAS) {
                v0.x = fmaxf(v0.x + b0.x, 0.f); v0.y = fmaxf(v0.y + b0.y, 0.f);
                v0.z = fmaxf(v0.z + b0.z, 0.f); v0.w = fmaxf(v0.w + b0.w, 0.f);
                v1.x = fmaxf(v1.x + b1.x, 0.f); v1.y = fmaxf(v1.y + b1.y, 0.f);
                v1.z = fmaxf(v1.z + b1.z, 0.f); v1.w = fmaxf(v1.w + b1.w, 0.f);
            }
            *(float4*)&C[(size_t)m * N + n0 + 8 * tc] = v0;
            *(float4*)&C[(size_t)m * N + n0 + 8 * tc + 4] = v1;
        }
    }
}

// ------- Layer 2 agg (wave-per-node) fused with bias+relu and final [128]->[2] GEMM -------
__global__ __launch_bounds__(256) void agg2_out(const float* __restrict__ z,
                                                const int* __restrict__ rp,
                                                const int* __restrict__ csr,
                                                const float* __restrict__ b2,
                                                const float* __restrict__ W3,
                                                const float* __restrict__ b3,
                                                float* __restrict__ out, int N) {
    int w = threadIdx.x >> 6, lane = threadIdx.x & 63;
    int n = blockIdx.x * 4 + w;
    if (n >= N) return;
    int s = rp[n], e = rp[n + 1];
    const float2* z2 = (const float2*)z;
    float2 a0 = {0.f, 0.f}, a1 = {0.f, 0.f}, a2 = {0.f, 0.f}, a3 = {0.f, 0.f};
    int i = s;
    for (; i + 3 < e; i += 4) {
        int s0 = csr[i], s1 = csr[i + 1], s2 = csr[i + 2], s3 = csr[i + 3];
        float2 v0 = z2[(size_t)s0 * 64 + lane];
        float2 v1 = z2[(size_t)s1 * 64 + lane];
        float2 v2 = z2[(size_t)s2 * 64 + lane];
        float2 v3 = z2[(size_t)s3 * 64 + lane];
        a0.x += v0.x; a0.y += v0.y; a1.x += v1.x; a1.y += v1.y;
        a2.x += v2.x; a2.y += v2.y; a3.x += v3.x; a3.y += v3.y;
    }
    for (; i < e; i++) {
        float2 v = z2[(size_t)csr[i] * 64 + lane];
        a0.x += v.x; a0.y += v.y;
    }
    float dinv = 1.f / fmaxf((float)(e - s), 1.f);
    float hx = fmaxf((a0.x + a1.x + a2.x + a3.x) * dinv + b2[2 * lane], 0.f);
    float hy = fmaxf((a0.y + a1.y + a2.y + a3.y) * dinv + b2[2 * lane + 1], 0.f);
    float p0 = hx * W3[2 * lane] + hy * W3[2 * lane + 1];
    float p1 = hx * W3[HID2 + 2 * lane] + hy * W3[HID2 + 2 * lane + 1];
#pragma unroll
    for (int d = 32; d > 0; d >>= 1) {
        p0 += __shfl_down(p0, d, 64);
        p1 += __shfl_down(p1, d, 64);
    }
    if (lane == 0) {
        out[(size_t)n * 2]     = p0 + b3[0];
        out[(size_t)n * 2 + 1] = p1 + b3[1];
    }
}

extern "C" void kernel_launch(void* const* d_in, const int* in_sizes, int n_in,
                              void* d_out, int out_size, void* d_ws, size_t ws_size,
                              hipStream_t stream) {
    const float* x  = (const float*)d_in[0];
    const int*   ei = (const int*)d_in[1];
    const float* W1 = (const float*)d_in[3];
    const float* b1 = (const float*)d_in[4];
    const float* W2 = (const float*)d_in[5];
    const float* b2 = (const float*)d_in[6];
    const float* W3 = (const float*)d_in[7];
    const float* b3 = (const float*)d_in[8];
    float* out = (float*)d_out;

    int N = in_sizes[0] / IN_F;   // 50000
    int E = in_sizes[1] / 2;      // 800000
    const int* row = ei;
    const int* col = ei + E;

    char* base = (char*)d_ws;
    size_t off = 0;
    auto alloc = [&](size_t bytes) -> void* {
        off = (off + 255) & ~(size_t)255;
        void* p = base + off;
        off += bytes;
        return p;
    };
    int*   deg  = (int*)alloc((size_t)2 * N * 4);   // deg + fill, one memset
    int*   fill = deg + N;
    int*   rp   = (int*)alloc((size_t)(N + 1) * 4);
    int*   tmp  = (int*)alloc((size_t)N * 4);
    int*   bsum = (int*)alloc(1024);
    int*   csr  = (int*)alloc((size_t)E * 4);
    float* h1   = (float*)alloc((size_t)N * HID * 4);
    float* f2   = (float*)alloc((size_t)N * IN_F * 4);  // agg1, later reused as z2

    hipMemsetAsync(deg, 0, (size_t)2 * N * 4, stream);
    int eb = (E + 255) / 256;
    int nb = (N + 255) / 256;   // 196
    count_deg<<<eb, 256, 0, stream>>>(col, deg, E);
    scan_block<<<nb, 256, 0, stream>>>(deg, tmp, bsum, N);
    scan_bsums<<<1, 256, 0, stream>>>(bsum, nb);
    scan_add<<<nb, 256, 0, stream>>>(tmp, bsum, rp, N);
    fill_csr<<<eb, 256, 0, stream>>>(row, col, rp, fill, csr, E);

    agg_gather<<<(N + 3) / 4, 256, 0, stream>>>(x, rp, csr, f2, N);

    // gemm1: BM=128 (MT=8), grid 391x2; gemm2: BM=64 (MT=4), grid 782x1
    gemm_t8<8, true><<<dim3((N + 127) / 128, HID / BN), 256, 0, stream>>>(f2, W1, b1, h1, N, HID, IN_F);
    gemm_t8<4, false><<<dim3((N + 63) / 64, HID2 / BN), 256, 0, stream>>>(h1, W2, nullptr, f2, N, HID2, HID);
    agg2_out<<<(N + 3) / 4, 256, 0, stream>>>(f2, rp, csr, b2, W3, b3, out, N);
}

// Round 5
// 409.979 us; speedup vs baseline: 1.3476x; 1.3476x over previous
//
#include <hip/hip_runtime.h>

#define IN_F 128
#define HID 256
#define HID2 128

#define BK 32
#define BN 128

// ---------------- CSR build ----------------
__global__ void count_deg(const int* __restrict__ col, int* __restrict__ deg, int E) {
    int e = blockIdx.x * blockDim.x + threadIdx.x;
    if (e < E) atomicAdd(&deg[col[e]], 1);
}

// 3-phase parallel exclusive scan
__global__ __launch_bounds__(256) void scan_block(const int* __restrict__ deg,
                                                  int* __restrict__ tmp,
                                                  int* __restrict__ bsum, int n) {
    int b = blockIdx.x, t = threadIdx.x, i = b * 256 + t;
    int lane = t & 63, w = t >> 6;
    int v = (i < n) ? deg[i] : 0;
    int x = v;
#pragma unroll
    for (int d = 1; d < 64; d <<= 1) {
        int y = __shfl_up(x, d, 64);
        if (lane >= d) x += y;
    }
    __shared__ int ws[4];
    if (lane == 63) ws[w] = x;
    __syncthreads();
    if (t < 4) {
        int s = ws[t];
#pragma unroll
        for (int d = 1; d < 4; d <<= 1) {
            int y = __shfl_up(s, d, 64);
            if (t >= d) s += y;
        }
        ws[t] = s;
    }
    __syncthreads();
    x += (w ? ws[w - 1] : 0);
    if (i < n) tmp[i] = x;
    if (t == 255) bsum[b] = x;
}

__global__ __launch_bounds__(256) void scan_bsums(int* __restrict__ bsum, int nb) {
    int t = threadIdx.x, lane = t & 63, w = t >> 6;
    int v = (t < nb) ? bsum[t] : 0;
    int x = v;
#pragma unroll
    for (int d = 1; d < 64; d <<= 1) {
        int y = __shfl_up(x, d, 64);
        if (lane >= d) x += y;
    }
    __shared__ int ws[4];
    if (lane == 63) ws[w] = x;
    __syncthreads();
    if (t < 4) {
        int s = ws[t];
#pragma unroll
        for (int d = 1; d < 4; d <<= 1) {
            int y = __shfl_up(s, d, 64);
            if (t >= d) s += y;
        }
        ws[t] = s;
    }
    __syncthreads();
    x += (w ? ws[w - 1] : 0);
    if (t < nb) bsum[t] = x;
}

__global__ void scan_add(const int* __restrict__ tmp, const int* __restrict__ bsum,
                         int* __restrict__ rp, int n) {
    int b = blockIdx.x, i = b * 256 + threadIdx.x;
    if (i < n) {
        rp[i + 1] = tmp[i] + (b ? bsum[b - 1] : 0);
        if (i == 0) rp[0] = 0;
    }
}

__global__ void fill_csr(const int* __restrict__ row, const int* __restrict__ col,
                         const int* __restrict__ rp, int* __restrict__ fill,
                         int* __restrict__ csr, int E) {
    int e = blockIdx.x * blockDim.x + threadIdx.x;
    if (e < E) {
        int c = col[e];
        int p = atomicAdd(&fill[c], 1);
        csr[rp[c] + p] = row[e];
    }
}

// ------- Layer 1 agg: wave-per-node, float4/lane, 2 edges per wave per load -------
// Row = 32 float4; lanes 0-31 handle even edge of a pair, 32-63 odd edge.
// Cross-half combine via __shfl_xor(...,32); half 0 writes the row.
__global__ __launch_bounds__(256) void agg_gather(const float* __restrict__ x,
                                                  const int* __restrict__ rp,
                                                  const int* __restrict__ csr,
                                                  float* __restrict__ out, int N) {
    int w = threadIdx.x >> 6, lane = threadIdx.x & 63;
    int n = blockIdx.x * 4 + w;
    if (n >= N) return;
    int s = rp[n], e = rp[n + 1];
    int half = lane >> 5, l = lane & 31;
    const float4* x4 = (const float4*)x;
    float4 a0 = {0,0,0,0}, a1 = {0,0,0,0}, a2 = {0,0,0,0}, a3 = {0,0,0,0};
    int i = s;
    for (; i + 7 < e; i += 8) {
        int s0 = csr[i + half], s1 = csr[i + 2 + half];
        int s2 = csr[i + 4 + half], s3 = csr[i + 6 + half];
        float4 v0 = x4[(size_t)s0 * 32 + l];
        float4 v1 = x4[(size_t)s1 * 32 + l];
        float4 v2 = x4[(size_t)s2 * 32 + l];
        float4 v3 = x4[(size_t)s3 * 32 + l];
        a0.x += v0.x; a0.y += v0.y; a0.z += v0.z; a0.w += v0.w;
        a1.x += v1.x; a1.y += v1.y; a1.z += v1.z; a1.w += v1.w;
        a2.x += v2.x; a2.y += v2.y; a2.z += v2.z; a2.w += v2.w;
        a3.x += v3.x; a3.y += v3.y; a3.z += v3.z; a3.w += v3.w;
    }
    for (; i + 1 < e; i += 2) {
        float4 v = x4[(size_t)csr[i + half] * 32 + l];
        a0.x += v.x; a0.y += v.y; a0.z += v.z; a0.w += v.w;
    }
    if (i < e && half == 0) {
        float4 v = x4[(size_t)csr[i] * 32 + l];
        a0.x += v.x; a0.y += v.y; a0.z += v.z; a0.w += v.w;
    }
    a0.x += a1.x + a2.x + a3.x; a0.y += a1.y + a2.y + a3.y;
    a0.z += a1.z + a2.z + a3.z; a0.w += a1.w + a2.w + a3.w;
    a0.x += __shfl_xor(a0.x, 32, 64);
    a0.y += __shfl_xor(a0.y, 32, 64);
    a0.z += __shfl_xor(a0.z, 32, 64);
    a0.w += __shfl_xor(a0.w, 32, 64);
    if (half == 0) {
        float dinv = 1.f / fmaxf((float)(e - s), 1.f);
        float4 o = make_float4(a0.x * dinv, a0.y * dinv, a0.z * dinv, a0.w * dinv);
        ((float4*)out)[(size_t)n * 32 + l] = o;
    }
}

// ---------------- GEMM: C[M,N] = A[M,K] @ W[N,K]^T (+bias,relu) ----------------
// 256 threads as 16x16 grid; micro-tile MT x 8, BN=128, k-major transposed LDS.
// NO min-occupancy bound: R4's (256,3) forced VGPR=84 and spilled the 64-reg
// accumulator to scratch (WRITE_SIZE 443 MB). ~110-130 VGPR fits 4 waves/SIMD.
template<int MT, bool RELU_BIAS>
__global__ __launch_bounds__(256) void gemm_t8(const float* __restrict__ A,
                                               const float* __restrict__ W,
                                               const float* __restrict__ bias,
                                               float* __restrict__ C,
                                               int M, int N, int K) {
    constexpr int BM = 16 * MT;
    constexpr int NA4 = BM / 32;
    __shared__ float As[BK][BM + 4];
    __shared__ float Ws[BK][BN + 4];
    int m0 = blockIdx.x * BM, n0 = blockIdx.y * BN;
    int t = threadIdx.x;
    int tr = t >> 4, tc = t & 15;

    int am[NA4], ak4[NA4];
#pragma unroll
    for (int it = 0; it < NA4; it++) { int id = t + 256 * it; am[it] = id >> 3; ak4[it] = id & 7; }
    int wn[4], wk4[4];
#pragma unroll
    for (int it = 0; it < 4; it++) { int id = t + 256 * it; wn[it] = id >> 3; wk4[it] = id & 7; }

    float4 av[NA4], wv[4];
    auto load_chunk = [&](int kc) {
#pragma unroll
        for (int it = 0; it < NA4; it++) {
            int m = m0 + am[it];
            av[it] = (m < M) ? *(const float4*)&A[(size_t)m * K + kc + 4 * ak4[it]]
                             : make_float4(0.f, 0.f, 0.f, 0.f);
        }
#pragma unroll
        for (int it = 0; it < 4; it++)
            wv[it] = *(const float4*)&W[(size_t)(n0 + wn[it]) * K + kc + 4 * wk4[it]];
    };

    load_chunk(0);
    float acc[MT][8];
#pragma unroll
    for (int i = 0; i < MT; i++)
#pragma unroll
        for (int j = 0; j < 8; j++) acc[i][j] = 0.f;

    for (int kc = 0; kc < K; kc += BK) {
        __syncthreads();
#pragma unroll
        for (int it = 0; it < NA4; it++) {
            As[4 * ak4[it] + 0][am[it]] = av[it].x;
            As[4 * ak4[it] + 1][am[it]] = av[it].y;
            As[4 * ak4[it] + 2][am[it]] = av[it].z;
            As[4 * ak4[it] + 3][am[it]] = av[it].w;
        }
#pragma unroll
        for (int it = 0; it < 4; it++) {
            Ws[4 * wk4[it] + 0][wn[it]] = wv[it].x;
            Ws[4 * wk4[it] + 1][wn[it]] = wv[it].y;
            Ws[4 * wk4[it] + 2][wn[it]] = wv[it].z;
            Ws[4 * wk4[it] + 3][wn[it]] = wv[it].w;
        }
        __syncthreads();
        if (kc + BK < K) load_chunk(kc + BK);
#pragma unroll
        for (int k = 0; k < BK; k++) {
            float4 w0 = *(const float4*)&Ws[k][8 * tc];
            float4 w1 = *(const float4*)&Ws[k][8 * tc + 4];
            float a[MT];
#pragma unroll
            for (int h = 0; h < MT / 4; h++) {
                float4 aq = *(const float4*)&As[k][MT * tr + 4 * h];
                a[4 * h] = aq.x; a[4 * h + 1] = aq.y; a[4 * h + 2] = aq.z; a[4 * h + 3] = aq.w;
            }
#pragma unroll
            for (int i = 0; i < MT; i++) {
                acc[i][0] += a[i] * w0.x; acc[i][1] += a[i] * w0.y;
                acc[i][2] += a[i] * w0.z; acc[i][3] += a[i] * w0.w;
                acc[i][4] += a[i] * w1.x; acc[i][5] += a[i] * w1.y;
                acc[i][6] += a[i] * w1.z; acc[i][7] += a[i] * w1.w;
            }
        }
    }

    float4 b0 = make_float4(0.f, 0.f, 0.f, 0.f), b1 = b0;
    if (RELU_BIAS) {
        b0 = *(const float4*)&bias[n0 + 8 * tc];
        b1 = *(const float4*)&bias[n0 + 8 * tc + 4];
    }
#pragma unroll
    for (int i = 0; i < MT; i++) {
        int m = m0 + MT * tr + i;
        if (m < M) {
            float4 v0 = make_float4(acc[i][0], acc[i][1], acc[i][2], acc[i][3]);
            float4 v1 = make_float4(acc[i][4], acc[i][5], acc[i][6], acc[i][7]);
            if (RELU_BIAS) {
                v0.x = fmaxf(v0.x + b0.x, 0.f); v0.y = fmaxf(v0.y + b0.y, 0.f);
                v0.z = fmaxf(v0.z + b0.z, 0.f); v0.w = fmaxf(v0.w + b0.w, 0.f);
                v1.x = fmaxf(v1.x + b1.x, 0.f); v1.y = fmaxf(v1.y + b1.y, 0.f);
                v1.z = fmaxf(v1.z + b1.z, 0.f); v1.w = fmaxf(v1.w + b1.w, 0.f);
            }
            *(float4*)&C[(size_t)m * N + n0 + 8 * tc] = v0;
            *(float4*)&C[(size_t)m * N + n0 + 8 * tc + 4] = v1;
        }
    }
}

// ------- Layer 2 agg (float4/lane, 2 edges/wave) + bias+relu + [128]->[2] GEMM -------
__global__ __launch_bounds__(256) void agg2_out(const float* __restrict__ z,
                                                const int* __restrict__ rp,
                                                const int* __restrict__ csr,
                                                const float* __restrict__ b2,
                                                const float* __restrict__ W3,
                                                const float* __restrict__ b3,
                                                float* __restrict__ out, int N) {
    int w = threadIdx.x >> 6, lane = threadIdx.x & 63;
    int n = blockIdx.x * 4 + w;
    if (n >= N) return;
    int s = rp[n], e = rp[n + 1];
    int half = lane >> 5, l = lane & 31;
    const float4* z4 = (const float4*)z;
    float4 a0 = {0,0,0,0}, a1 = {0,0,0,0}, a2 = {0,0,0,0}, a3 = {0,0,0,0};
    int i = s;
    for (; i + 7 < e; i += 8) {
        int s0 = csr[i + half], s1 = csr[i + 2 + half];
        int s2 = csr[i + 4 + half], s3 = csr[i + 6 + half];
        float4 v0 = z4[(size_t)s0 * 32 + l];
        float4 v1 = z4[(size_t)s1 * 32 + l];
        float4 v2 = z4[(size_t)s2 * 32 + l];
        float4 v3 = z4[(size_t)s3 * 32 + l];
        a0.x += v0.x; a0.y += v0.y; a0.z += v0.z; a0.w += v0.w;
        a1.x += v1.x; a1.y += v1.y; a1.z += v1.z; a1.w += v1.w;
        a2.x += v2.x; a2.y += v2.y; a2.z += v2.z; a2.w += v2.w;
        a3.x += v3.x; a3.y += v3.y; a3.z += v3.z; a3.w += v3.w;
    }
    for (; i + 1 < e; i += 2) {
        float4 v = z4[(size_t)csr[i + half] * 32 + l];
        a0.x += v.x; a0.y += v.y; a0.z += v.z; a0.w += v.w;
    }
    if (i < e && half == 0) {
        float4 v = z4[(size_t)csr[i] * 32 + l];
        a0.x += v.x; a0.y += v.y; a0.z += v.z; a0.w += v.w;
    }
    a0.x += a1.x + a2.x + a3.x; a0.y += a1.y + a2.y + a3.y;
    a0.z += a1.z + a2.z + a3.z; a0.w += a1.w + a2.w + a3.w;
    a0.x += __shfl_xor(a0.x, 32, 64);
    a0.y += __shfl_xor(a0.y, 32, 64);
    a0.z += __shfl_xor(a0.z, 32, 64);
    a0.w += __shfl_xor(a0.w, 32, 64);
    // all lanes now hold agg for cols 4l..4l+3; halves compute the two output dots
    float dinv = 1.f / fmaxf((float)(e - s), 1.f);
    float4 bb = ((const float4*)b2)[l];
    float4 ww = ((const float4*)W3)[half * 32 + l];
    float hx = fmaxf(a0.x * dinv + bb.x, 0.f);
    float hy = fmaxf(a0.y * dinv + bb.y, 0.f);
    float hz = fmaxf(a0.z * dinv + bb.z, 0.f);
    float hw = fmaxf(a0.w * dinv + bb.w, 0.f);
    float p = hx * ww.x + hy * ww.y + hz * ww.z + hw * ww.w;
#pragma unroll
    for (int d = 16; d > 0; d >>= 1) p += __shfl_xor(p, d, 64);
    if (l == 0) out[(size_t)n * 2 + half] = p + b3[half];
}

extern "C" void kernel_launch(void* const* d_in, const int* in_sizes, int n_in,
                              void* d_out, int out_size, void* d_ws, size_t ws_size,
                              hipStream_t stream) {
    const float* x  = (const float*)d_in[0];
    const int*   ei = (const int*)d_in[1];
    const float* W1 = (const float*)d_in[3];
    const float* b1 = (const float*)d_in[4];
    const float* W2 = (const float*)d_in[5];
    const float* b2 = (const float*)d_in[6];
    const float* W3 = (const float*)d_in[7];
    const float* b3 = (const float*)d_in[8];
    float* out = (float*)d_out;

    int N = in_sizes[0] / IN_F;   // 50000
    int E = in_sizes[1] / 2;      // 800000
    const int* row = ei;
    const int* col = ei + E;

    char* base = (char*)d_ws;
    size_t off = 0;
    auto alloc = [&](size_t bytes) -> void* {
        off = (off + 255) & ~(size_t)255;
        void* p = base + off;
        off += bytes;
        return p;
    };
    int*   deg  = (int*)alloc((size_t)2 * N * 4);   // deg + fill, one memset
    int*   fill = deg + N;
    int*   rp   = (int*)alloc((size_t)(N + 1) * 4);
    int*   tmp  = (int*)alloc((size_t)N * 4);
    int*   bsum = (int*)alloc(1024);
    int*   csr  = (int*)alloc((size_t)E * 4);
    float* h1   = (float*)alloc((size_t)N * HID * 4);
    float* f2   = (float*)alloc((size_t)N * IN_F * 4);  // agg1, later reused as z2

    hipMemsetAsync(deg, 0, (size_t)2 * N * 4, stream);
    int eb = (E + 255) / 256;
    int nb = (N + 255) / 256;   // 196
    count_deg<<<eb, 256, 0, stream>>>(col, deg, E);
    scan_block<<<nb, 256, 0, stream>>>(deg, tmp, bsum, N);
    scan_bsums<<<1, 256, 0, stream>>>(bsum, nb);
    scan_add<<<nb, 256, 0, stream>>>(tmp, bsum, rp, N);
    fill_csr<<<eb, 256, 0, stream>>>(row, col, rp, fill, csr, E);

    agg_gather<<<(N + 3) / 4, 256, 0, stream>>>(x, rp, csr, f2, N);

    gemm_t8<8, true><<<dim3((N + 127) / 128, HID / BN), 256, 0, stream>>>(f2, W1, b1, h1, N, HID, IN_F);
    gemm_t8<4, false><<<dim3((N + 63) / 64, HID2 / BN), 256, 0, stream>>>(h1, W2, nullptr, f2, N, HID2, HID);
    agg2_out<<<(N + 3) / 4, 256, 0, stream>>>(f2, rp, csr, b2, W3, b3, out, N);
}

// Round 6
// 344.762 us; speedup vs baseline: 1.6025x; 1.1892x over previous
//
#include <hip/hip_runtime.h>

#define IN_F 128
#define HID 256
#define HID2 128

typedef __attribute__((ext_vector_type(8))) short bf16x8;
typedef __attribute__((ext_vector_type(4))) float f32x4;

// ---------------- CSR build ----------------
__global__ void count_deg(const int* __restrict__ col, int* __restrict__ deg, int E) {
    int e = blockIdx.x * blockDim.x + threadIdx.x;
    if (e < E) atomicAdd(&deg[col[e]], 1);
}

// 3-phase parallel exclusive scan
__global__ __launch_bounds__(256) void scan_block(const int* __restrict__ deg,
                                                  int* __restrict__ tmp,
                                                  int* __restrict__ bsum, int n) {
    int b = blockIdx.x, t = threadIdx.x, i = b * 256 + t;
    int lane = t & 63, w = t >> 6;
    int v = (i < n) ? deg[i] : 0;
    int x = v;
#pragma unroll
    for (int d = 1; d < 64; d <<= 1) {
        int y = __shfl_up(x, d, 64);
        if (lane >= d) x += y;
    }
    __shared__ int ws[4];
    if (lane == 63) ws[w] = x;
    __syncthreads();
    if (t < 4) {
        int s = ws[t];
#pragma unroll
        for (int d = 1; d < 4; d <<= 1) {
            int y = __shfl_up(s, d, 64);
            if (t >= d) s += y;
        }
        ws[t] = s;
    }
    __syncthreads();
    x += (w ? ws[w - 1] : 0);
    if (i < n) tmp[i] = x;
    if (t == 255) bsum[b] = x;
}

__global__ __launch_bounds__(256) void scan_bsums(int* __restrict__ bsum, int nb) {
    int t = threadIdx.x, lane = t & 63, w = t >> 6;
    int v = (t < nb) ? bsum[t] : 0;
    int x = v;
#pragma unroll
    for (int d = 1; d < 64; d <<= 1) {
        int y = __shfl_up(x, d, 64);
        if (lane >= d) x += y;
    }
    __shared__ int ws[4];
    if (lane == 63) ws[w] = x;
    __syncthreads();
    if (t < 4) {
        int s = ws[t];
#pragma unroll
        for (int d = 1; d < 4; d <<= 1) {
            int y = __shfl_up(s, d, 64);
            if (t >= d) s += y;
        }
        ws[t] = s;
    }
    __syncthreads();
    x += (w ? ws[w - 1] : 0);
    if (t < nb) bsum[t] = x;
}

__global__ void scan_add(const int* __restrict__ tmp, const int* __restrict__ bsum,
                         int* __restrict__ rp, int n) {
    int b = blockIdx.x, i = b * 256 + threadIdx.x;
    if (i < n) {
        rp[i + 1] = tmp[i] + (b ? bsum[b - 1] : 0);
        if (i == 0) rp[0] = 0;
    }
}

__global__ void fill_csr(const int* __restrict__ row, const int* __restrict__ col,
                         const int* __restrict__ rp, int* __restrict__ fill,
                         int* __restrict__ csr, int E) {
    int e = blockIdx.x * blockDim.x + threadIdx.x;
    if (e < E) {
        int c = col[e];
        int p = atomicAdd(&fill[c], 1);
        csr[rp[c] + p] = row[e];
    }
}

// ------- Layer 1 agg: wave-per-node, float4/lane, 2 edges per wave per load -------
__global__ __launch_bounds__(256) void agg_gather(const float* __restrict__ x,
                                                  const int* __restrict__ rp,
                                                  const int* __restrict__ csr,
                                                  float* __restrict__ out, int N) {
    int w = threadIdx.x >> 6, lane = threadIdx.x & 63;
    int n = blockIdx.x * 4 + w;
    if (n >= N) return;
    int s = rp[n], e = rp[n + 1];
    int half = lane >> 5, l = lane & 31;
    const float4* x4 = (const float4*)x;
    float4 a0 = {0,0,0,0}, a1 = {0,0,0,0}, a2 = {0,0,0,0}, a3 = {0,0,0,0};
    int i = s;
    for (; i + 7 < e; i += 8) {
        int s0 = csr[i + half], s1 = csr[i + 2 + half];
        int s2 = csr[i + 4 + half], s3 = csr[i + 6 + half];
        float4 v0 = x4[(size_t)s0 * 32 + l];
        float4 v1 = x4[(size_t)s1 * 32 + l];
        float4 v2 = x4[(size_t)s2 * 32 + l];
        float4 v3 = x4[(size_t)s3 * 32 + l];
        a0.x += v0.x; a0.y += v0.y; a0.z += v0.z; a0.w += v0.w;
        a1.x += v1.x; a1.y += v1.y; a1.z += v1.z; a1.w += v1.w;
        a2.x += v2.x; a2.y += v2.y; a2.z += v2.z; a2.w += v2.w;
        a3.x += v3.x; a3.y += v3.y; a3.z += v3.z; a3.w += v3.w;
    }
    for (; i + 1 < e; i += 2) {
        float4 v = x4[(size_t)csr[i + half] * 32 + l];
        a0.x += v.x; a0.y += v.y; a0.z += v.z; a0.w += v.w;
    }
    if (i < e && half == 0) {
        float4 v = x4[(size_t)csr[i] * 32 + l];
        a0.x += v.x; a0.y += v.y; a0.z += v.z; a0.w += v.w;
    }
    a0.x += a1.x + a2.x + a3.x; a0.y += a1.y + a2.y + a3.y;
    a0.z += a1.z + a2.z + a3.z; a0.w += a1.w + a2.w + a3.w;
    a0.x += __shfl_xor(a0.x, 32, 64);
    a0.y += __shfl_xor(a0.y, 32, 64);
    a0.z += __shfl_xor(a0.z, 32, 64);
    a0.w += __shfl_xor(a0.w, 32, 64);
    if (half == 0) {
        float dinv = 1.f / fmaxf((float)(e - s), 1.f);
        float4 o = make_float4(a0.x * dinv, a0.y * dinv, a0.z * dinv, a0.w * dinv);
        ((float4*)out)[(size_t)n * 32 + l] = o;
    }
}

// ------- split fp32 weights into hi/lo bf16 (truncation split) -------
__global__ void split_weights(const float* __restrict__ W1, const float* __restrict__ W2,
                              ushort* __restrict__ w1h, ushort* __restrict__ w1l,
                              ushort* __restrict__ w2h, ushort* __restrict__ w2l) {
    int i = blockIdx.x * 256 + threadIdx.x;   // 0..65535
    bool first = i < 32768;
    int j = i & 32767;
    float f = first ? W1[j] : W2[j];
    unsigned u = __float_as_uint(f);
    float hf = __uint_as_float(u & 0xffff0000u);
    unsigned lo = __float_as_uint(f - hf);
    ushort hs = (ushort)(u >> 16), ls = (ushort)(lo >> 16);
    if (first) { w1h[j] = hs; w1l[j] = ls; }
    else       { w2h[j] = hs; w2l[j] = ls; }
}

// ---------------- MFMA GEMM: C[M,N] = A[M,K] @ W[N,K]^T (+bias,relu) ----------------
// Split-fp32 via bf16: A*W ~= Ah*Wh + Ah*Wl + Al*Wh (Al*Wl ~2^-16, dropped).
// 256 threads = 4 waves in 2x2 over a 128x128 C-tile; 4x4 mfma_16x16x32 per wave.
// No LDS, no barriers: fragments load straight from global (k-major rows; A and W
// operand layouts identical: lane l -> row l&15, k = (l>>4)*8 + e).
// A is fp32, split in-register; W pre-split in memory.
// C/D layout (m89-verified): col = lane&15, row = (lane>>4)*4 + reg.
template<bool RELU_BIAS>
__global__ __launch_bounds__(256) void gemm_mfma(const float* __restrict__ A,
                                                 const ushort* __restrict__ Wh,
                                                 const ushort* __restrict__ Wl,
                                                 const float* __restrict__ bias,
                                                 float* __restrict__ C,
                                                 int M, int N, int K) {
    int t = threadIdx.x;
    int wv = t >> 6, l = t & 63;
    int r = l & 15, q = l >> 4;
    int m0 = blockIdx.x * 128 + (wv >> 1) * 64;
    int n0 = blockIdx.y * 128 + (wv & 1) * 64;

    f32x4 acc[4][4];
#pragma unroll
    for (int i = 0; i < 4; i++)
#pragma unroll
        for (int j = 0; j < 4; j++) acc[i][j] = (f32x4){0.f, 0.f, 0.f, 0.f};

    for (int k0 = 0; k0 < K; k0 += 32) {
        int kf = k0 + q * 8;
        bf16x8 ah[4], al[4], wh[4], wl[4];
#pragma unroll
        for (int i = 0; i < 4; i++) {
            int m = m0 + 16 * i + r;
            if (m > M - 1) m = M - 1;               // clamp tail rows (stores guarded)
            const float* ap = A + (size_t)m * K + kf;
            float4 f0 = *(const float4*)ap;
            float4 f1 = *(const float4*)(ap + 4);
            float fe[8] = {f0.x, f0.y, f0.z, f0.w, f1.x, f1.y, f1.z, f1.w};
#pragma unroll
            for (int e = 0; e < 8; e++) {
                unsigned u = __float_as_uint(fe[e]);
                float hf = __uint_as_float(u & 0xffff0000u);
                unsigned lo = __float_as_uint(fe[e] - hf);
                ah[i][e] = (short)(u >> 16);
                al[i][e] = (short)(lo >> 16);
            }
        }
#pragma unroll
        for (int j = 0; j < 4; j++) {
            size_t wo = (size_t)(n0 + 16 * j + r) * K + kf;
            wh[j] = *(const bf16x8*)(Wh + wo);
            wl[j] = *(const bf16x8*)(Wl + wo);
        }
#pragma unroll
        for (int i = 0; i < 4; i++)
#pragma unroll
            for (int j = 0; j < 4; j++) {
                acc[i][j] = __builtin_amdgcn_mfma_f32_16x16x32_bf16(ah[i], wh[j], acc[i][j], 0, 0, 0);
                acc[i][j] = __builtin_amdgcn_mfma_f32_16x16x32_bf16(ah[i], wl[j], acc[i][j], 0, 0, 0);
                acc[i][j] = __builtin_amdgcn_mfma_f32_16x16x32_bf16(al[i], wh[j], acc[i][j], 0, 0, 0);
            }
    }

#pragma unroll
    for (int i = 0; i < 4; i++) {
#pragma unroll
        for (int reg = 0; reg < 4; reg++) {
            int m = m0 + 16 * i + q * 4 + reg;
            if (m < M) {
#pragma unroll
                for (int j = 0; j < 4; j++) {
                    int n = n0 + 16 * j + r;
                    float v = acc[i][j][reg];
                    if (RELU_BIAS) v = fmaxf(v + bias[n], 0.f);
                    C[(size_t)m * N + n] = v;
                }
            }
        }
    }
}

// ------- Layer 2 agg (float4/lane, 2 edges/wave) + bias+relu + [128]->[2] GEMM -------
__global__ __launch_bounds__(256) void agg2_out(const float* __restrict__ z,
                                                const int* __restrict__ rp,
                                                const int* __restrict__ csr,
                                                const float* __restrict__ b2,
                                                const float* __restrict__ W3,
                                                const float* __restrict__ b3,
                                                float* __restrict__ out, int N) {
    int w = threadIdx.x >> 6, lane = threadIdx.x & 63;
    int n = blockIdx.x * 4 + w;
    if (n >= N) return;
    int s = rp[n], e = rp[n + 1];
    int half = lane >> 5, l = lane & 31;
    const float4* z4 = (const float4*)z;
    float4 a0 = {0,0,0,0}, a1 = {0,0,0,0}, a2 = {0,0,0,0}, a3 = {0,0,0,0};
    int i = s;
    for (; i + 7 < e; i += 8) {
        int s0 = csr[i + half], s1 = csr[i + 2 + half];
        int s2 = csr[i + 4 + half], s3 = csr[i + 6 + half];
        float4 v0 = z4[(size_t)s0 * 32 + l];
        float4 v1 = z4[(size_t)s1 * 32 + l];
        float4 v2 = z4[(size_t)s2 * 32 + l];
        float4 v3 = z4[(size_t)s3 * 32 + l];
        a0.x += v0.x; a0.y += v0.y; a0.z += v0.z; a0.w += v0.w;
        a1.x += v1.x; a1.y += v1.y; a1.z += v1.z; a1.w += v1.w;
        a2.x += v2.x; a2.y += v2.y; a2.z += v2.z; a2.w += v2.w;
        a3.x += v3.x; a3.y += v3.y; a3.z += v3.z; a3.w += v3.w;
    }
    for (; i + 1 < e; i += 2) {
        float4 v = z4[(size_t)csr[i + half] * 32 + l];
        a0.x += v.x; a0.y += v.y; a0.z += v.z; a0.w += v.w;
    }
    if (i < e && half == 0) {
        float4 v = z4[(size_t)csr[i] * 32 + l];
        a0.x += v.x; a0.y += v.y; a0.z += v.z; a0.w += v.w;
    }
    a0.x += a1.x + a2.x + a3.x; a0.y += a1.y + a2.y + a3.y;
    a0.z += a1.z + a2.z + a3.z; a0.w += a1.w + a2.w + a3.w;
    a0.x += __shfl_xor(a0.x, 32, 64);
    a0.y += __shfl_xor(a0.y, 32, 64);
    a0.z += __shfl_xor(a0.z, 32, 64);
    a0.w += __shfl_xor(a0.w, 32, 64);
    float dinv = 1.f / fmaxf((float)(e - s), 1.f);
    float4 bb = ((const float4*)b2)[l];
    float4 ww = ((const float4*)W3)[half * 32 + l];
    float hx = fmaxf(a0.x * dinv + bb.x, 0.f);
    float hy = fmaxf(a0.y * dinv + bb.y, 0.f);
    float hz = fmaxf(a0.z * dinv + bb.z, 0.f);
    float hw = fmaxf(a0.w * dinv + bb.w, 0.f);
    float p = hx * ww.x + hy * ww.y + hz * ww.z + hw * ww.w;
#pragma unroll
    for (int d = 16; d > 0; d >>= 1) p += __shfl_xor(p, d, 64);
    if (l == 0) out[(size_t)n * 2 + half] = p + b3[half];
}

extern "C" void kernel_launch(void* const* d_in, const int* in_sizes, int n_in,
                              void* d_out, int out_size, void* d_ws, size_t ws_size,
                              hipStream_t stream) {
    const float* x  = (const float*)d_in[0];
    const int*   ei = (const int*)d_in[1];
    const float* W1 = (const float*)d_in[3];
    const float* b1 = (const float*)d_in[4];
    const float* W2 = (const float*)d_in[5];
    const float* b2 = (const float*)d_in[6];
    const float* W3 = (const float*)d_in[7];
    const float* b3 = (const float*)d_in[8];
    float* out = (float*)d_out;

    int N = in_sizes[0] / IN_F;   // 50000
    int E = in_sizes[1] / 2;      // 800000
    const int* row = ei;
    const int* col = ei + E;

    char* base = (char*)d_ws;
    size_t off = 0;
    auto alloc = [&](size_t bytes) -> void* {
        off = (off + 255) & ~(size_t)255;
        void* p = base + off;
        off += bytes;
        return p;
    };
    int*    deg  = (int*)alloc((size_t)2 * N * 4);   // deg + fill, one memset
    int*    fill = deg + N;
    int*    rp   = (int*)alloc((size_t)(N + 1) * 4);
    int*    tmp  = (int*)alloc((size_t)N * 4);
    int*    bsum = (int*)alloc(1024);
    int*    csr  = (int*)alloc((size_t)E * 4);
    float*  h1   = (float*)alloc((size_t)N * HID * 4);
    float*  f2   = (float*)alloc((size_t)N * IN_F * 4);  // agg1, later reused as z2
    ushort* w1h  = (ushort*)alloc(HID * IN_F * 2);
    ushort* w1l  = (ushort*)alloc(HID * IN_F * 2);
    ushort* w2h  = (ushort*)alloc(HID2 * HID * 2);
    ushort* w2l  = (ushort*)alloc(HID2 * HID * 2);

    hipMemsetAsync(deg, 0, (size_t)2 * N * 4, stream);
    int eb = (E + 255) / 256;
    int nb = (N + 255) / 256;   // 196
    count_deg<<<eb, 256, 0, stream>>>(col, deg, E);
    scan_block<<<nb, 256, 0, stream>>>(deg, tmp, bsum, N);
    scan_bsums<<<1, 256, 0, stream>>>(bsum, nb);
    scan_add<<<nb, 256, 0, stream>>>(tmp, bsum, rp, N);
    fill_csr<<<eb, 256, 0, stream>>>(row, col, rp, fill, csr, E);

    split_weights<<<256, 256, 0, stream>>>(W1, W2, w1h, w1l, w2h, w2l);
    agg_gather<<<(N + 3) / 4, 256, 0, stream>>>(x, rp, csr, f2, N);

    int mb = (N + 127) / 128;  // 391
    gemm_mfma<true><<<dim3(mb, HID / 128), 256, 0, stream>>>(f2, w1h, w1l, b1, h1, N, HID, IN_F);
    gemm_mfma<false><<<dim3(mb, HID2 / 128), 256, 0, stream>>>(h1, w2h, w2l, nullptr, f2, N, HID2, HID);
    agg2_out<<<(N + 3) / 4, 256, 0, stream>>>(f2, rp, csr, b2, W3, b3, out, N);
}

// Round 8
// 322.167 us; speedup vs baseline: 1.7149x; 1.0701x over previous
//
#include <hip/hip_runtime.h>
#include <hip/hip_fp16.h>

#define IN_F 128
#define HID 256
#define HID2 128

typedef __attribute__((ext_vector_type(8))) short bf16x8;
typedef __attribute__((ext_vector_type(4))) float f32x4;

// ---------------- CSR build ----------------
__global__ void count_deg(const int* __restrict__ col, int* __restrict__ deg, int E) {
    int e = blockIdx.x * blockDim.x + threadIdx.x;
    if (e < E) atomicAdd(&deg[col[e]], 1);
}

__global__ __launch_bounds__(256) void scan_block(const int* __restrict__ deg,
                                                  int* __restrict__ tmp,
                                                  int* __restrict__ bsum, int n) {
    int b = blockIdx.x, t = threadIdx.x, i = b * 256 + t;
    int lane = t & 63, w = t >> 6;
    int v = (i < n) ? deg[i] : 0;
    int x = v;
#pragma unroll
    for (int d = 1; d < 64; d <<= 1) {
        int y = __shfl_up(x, d, 64);
        if (lane >= d) x += y;
    }
    __shared__ int ws[4];
    if (lane == 63) ws[w] = x;
    __syncthreads();
    if (t < 4) {
        int s = ws[t];
#pragma unroll
        for (int d = 1; d < 4; d <<= 1) {
            int y = __shfl_up(s, d, 64);
            if (t >= d) s += y;
        }
        ws[t] = s;
    }
    __syncthreads();
    x += (w ? ws[w - 1] : 0);
    if (i < n) tmp[i] = x;
    if (t == 255) bsum[b] = x;
}

__global__ __launch_bounds__(256) void scan_bsums(int* __restrict__ bsum, int nb) {
    int t = threadIdx.x, lane = t & 63, w = t >> 6;
    int v = (t < nb) ? bsum[t] : 0;
    int x = v;
#pragma unroll
    for (int d = 1; d < 64; d <<= 1) {
        int y = __shfl_up(x, d, 64);
        if (lane >= d) x += y;
    }
    __shared__ int ws[4];
    if (lane == 63) ws[w] = x;
    __syncthreads();
    if (t < 4) {
        int s = ws[t];
#pragma unroll
        for (int d = 1; d < 4; d <<= 1) {
            int y = __shfl_up(s, d, 64);
            if (t >= d) s += y;
        }
        ws[t] = s;
    }
    __syncthreads();
    x += (w ? ws[w - 1] : 0);
    if (t < nb) bsum[t] = x;
}

__global__ void scan_add(const int* __restrict__ tmp, const int* __restrict__ bsum,
                         int* __restrict__ rp, int n) {
    int b = blockIdx.x, i = b * 256 + threadIdx.x;
    if (i < n) {
        rp[i + 1] = tmp[i] + (b ? bsum[b - 1] : 0);
        if (i == 0) rp[0] = 0;
    }
}

__global__ void fill_csr(const int* __restrict__ row, const int* __restrict__ col,
                         const int* __restrict__ rp, int* __restrict__ fill,
                         int* __restrict__ csr, int E) {
    int e = blockIdx.x * blockDim.x + threadIdx.x;
    if (e < E) {
        int c = col[e];
        int p = atomicAdd(&fill[c], 1);
        csr[rp[c] + p] = row[e];
    }
}

// ------- fp32 -> fp16 pack, 8 elements per thread -------
__global__ void to_f16(const float* __restrict__ src, ushort* __restrict__ dst, int total8) {
    int i = blockIdx.x * 256 + threadIdx.x;
    if (i >= total8) return;
    const float4* s4 = (const float4*)src + (size_t)i * 2;
    float4 f0 = s4[0], f1 = s4[1];
    uint4 o;
    o.x = __half_as_ushort(__float2half(f0.x)) | ((unsigned)__half_as_ushort(__float2half(f0.y)) << 16);
    o.y = __half_as_ushort(__float2half(f0.z)) | ((unsigned)__half_as_ushort(__float2half(f0.w)) << 16);
    o.z = __half_as_ushort(__float2half(f1.x)) | ((unsigned)__half_as_ushort(__float2half(f1.y)) << 16);
    o.w = __half_as_ushort(__float2half(f1.z)) | ((unsigned)__half_as_ushort(__float2half(f1.w)) << 16);
    ((uint4*)dst)[i] = o;
}

// ------- split fp32 weights into hi/lo bf16 (truncation split) — R6 verbatim -------
__global__ void split_weights(const float* __restrict__ W1, const float* __restrict__ W2,
                              ushort* __restrict__ w1h, ushort* __restrict__ w1l,
                              ushort* __restrict__ w2h, ushort* __restrict__ w2l) {
    int i = blockIdx.x * 256 + threadIdx.x;   // 0..65535
    bool first = i < 32768;
    int j = i & 32767;
    float f = first ? W1[j] : W2[j];
    unsigned u = __float_as_uint(f);
    float hf = __uint_as_float(u & 0xffff0000u);
    unsigned lo = __float_as_uint(f - hf);
    ushort hs = (ushort)(u >> 16), ls = (ushort)(lo >> 16);
    if (first) { w1h[j] = hs; w1l[j] = ls; }
    else       { w2h[j] = hs; w2l[j] = ls; }
}

// unpack uint2 (4 fp16) and accumulate into float4
__device__ __forceinline__ void add4h(float4& a, uint2 v) {
    float2 f0 = __half22float2(*(const __half2*)&v.x);
    float2 f1 = __half22float2(*(const __half2*)&v.y);
    a.x += f0.x; a.y += f0.y; a.z += f1.x; a.w += f1.y;
}

// ------- Layer 1 agg: R6 skeleton (wave-per-node, 32 lanes/row, 2 edges/step,
//         4-deep unroll), fp16 table: uint2/lane (features 4l..4l+3). fp32 out. -------
__global__ __launch_bounds__(256) void agg_gather(const ushort* __restrict__ xh,
                                                  const int* __restrict__ rp,
                                                  const int* __restrict__ csr,
                                                  float* __restrict__ out, int N) {
    int w = threadIdx.x >> 6, lane = threadIdx.x & 63;
    int n = blockIdx.x * 4 + w;
    if (n >= N) return;
    int s = rp[n], e = rp[n + 1];
    int half = lane >> 5, l = lane & 31;
    const uint2* xv = (const uint2*)xh;   // row = 32 uint2
    float4 a0 = {0,0,0,0}, a1 = {0,0,0,0}, a2 = {0,0,0,0}, a3 = {0,0,0,0};
    int i = s;
    for (; i + 7 < e; i += 8) {
        int s0 = csr[i + half], s1 = csr[i + 2 + half];
        int s2 = csr[i + 4 + half], s3 = csr[i + 6 + half];
        uint2 v0 = xv[(size_t)s0 * 32 + l];
        uint2 v1 = xv[(size_t)s1 * 32 + l];
        uint2 v2 = xv[(size_t)s2 * 32 + l];
        uint2 v3 = xv[(size_t)s3 * 32 + l];
        add4h(a0, v0); add4h(a1, v1); add4h(a2, v2); add4h(a3, v3);
    }
    for (; i + 1 < e; i += 2) {
        add4h(a0, xv[(size_t)csr[i + half] * 32 + l]);
    }
    if (i < e && half == 0) {
        add4h(a0, xv[(size_t)csr[i] * 32 + l]);
    }
    a0.x += a1.x + a2.x + a3.x; a0.y += a1.y + a2.y + a3.y;
    a0.z += a1.z + a2.z + a3.z; a0.w += a1.w + a2.w + a3.w;
    a0.x += __shfl_xor(a0.x, 32, 64);
    a0.y += __shfl_xor(a0.y, 32, 64);
    a0.z += __shfl_xor(a0.z, 32, 64);
    a0.w += __shfl_xor(a0.w, 32, 64);
    if (half == 0) {
        float dinv = 1.f / fmaxf((float)(e - s), 1.f);
        float4 o = make_float4(a0.x * dinv, a0.y * dinv, a0.z * dinv, a0.w * dinv);
        ((float4*)out)[(size_t)n * 32 + l] = o;
    }
}

// ---------------- MFMA GEMM — R6 verbatim (fp32 A split in-register, 3 passes) ----------------
template<bool RELU_BIAS>
__global__ __launch_bounds__(256) void gemm_mfma(const float* __restrict__ A,
                                                 const ushort* __restrict__ Wh,
                                                 const ushort* __restrict__ Wl,
                                                 const float* __restrict__ bias,
                                                 float* __restrict__ C,
                                                 int M, int N, int K) {
    int t = threadIdx.x;
    int wv = t >> 6, l = t & 63;
    int r = l & 15, q = l >> 4;
    int m0 = blockIdx.x * 128 + (wv >> 1) * 64;
    int n0 = blockIdx.y * 128 + (wv & 1) * 64;

    f32x4 acc[4][4];
#pragma unroll
    for (int i = 0; i < 4; i++)
#pragma unroll
        for (int j = 0; j < 4; j++) acc[i][j] = (f32x4){0.f, 0.f, 0.f, 0.f};

    for (int k0 = 0; k0 < K; k0 += 32) {
        int kf = k0 + q * 8;
        bf16x8 ah[4], al[4], wh[4], wl[4];
#pragma unroll
        for (int i = 0; i < 4; i++) {
            int m = m0 + 16 * i + r;
            if (m > M - 1) m = M - 1;               // clamp tail rows (stores guarded)
            const float* ap = A + (size_t)m * K + kf;
            float4 f0 = *(const float4*)ap;
            float4 f1 = *(const float4*)(ap + 4);
            float fe[8] = {f0.x, f0.y, f0.z, f0.w, f1.x, f1.y, f1.z, f1.w};
#pragma unroll
            for (int e = 0; e < 8; e++) {
                unsigned u = __float_as_uint(fe[e]);
                float hf = __uint_as_float(u & 0xffff0000u);
                unsigned lo = __float_as_uint(fe[e] - hf);
                ah[i][e] = (short)(u >> 16);
                al[i][e] = (short)(lo >> 16);
            }
        }
#pragma unroll
        for (int j = 0; j < 4; j++) {
            size_t wo = (size_t)(n0 + 16 * j + r) * K + kf;
            wh[j] = *(const bf16x8*)(Wh + wo);
            wl[j] = *(const bf16x8*)(Wl + wo);
        }
#pragma unroll
        for (int i = 0; i < 4; i++)
#pragma unroll
            for (int j = 0; j < 4; j++) {
                acc[i][j] = __builtin_amdgcn_mfma_f32_16x16x32_bf16(ah[i], wh[j], acc[i][j], 0, 0, 0);
                acc[i][j] = __builtin_amdgcn_mfma_f32_16x16x32_bf16(ah[i], wl[j], acc[i][j], 0, 0, 0);
                acc[i][j] = __builtin_amdgcn_mfma_f32_16x16x32_bf16(al[i], wh[j], acc[i][j], 0, 0, 0);
            }
    }

#pragma unroll
    for (int i = 0; i < 4; i++) {
#pragma unroll
        for (int reg = 0; reg < 4; reg++) {
            int m = m0 + 16 * i + q * 4 + reg;
            if (m < M) {
#pragma unroll
                for (int j = 0; j < 4; j++) {
                    int n = n0 + 16 * j + r;
                    float v = acc[i][j][reg];
                    if (RELU_BIAS) v = fmaxf(v + bias[n], 0.f);
                    C[(size_t)m * N + n] = v;
                }
            }
        }
    }
}

// ------- Layer 2 agg: R6 skeleton, fp16 z table, fused bias+relu + [128]->[2] GEMM -------
__global__ __launch_bounds__(256) void agg2_out(const ushort* __restrict__ zh,
                                                const int* __restrict__ rp,
                                                const int* __restrict__ csr,
                                                const float* __restrict__ b2,
                                                const float* __restrict__ W3,
                                                const float* __restrict__ b3,
                                                float* __restrict__ out, int N) {
    int w = threadIdx.x >> 6, lane = threadIdx.x & 63;
    int n = blockIdx.x * 4 + w;
    if (n >= N) return;
    int s = rp[n], e = rp[n + 1];
    int half = lane >> 5, l = lane & 31;
    const uint2* zv = (const uint2*)zh;
    float4 a0 = {0,0,0,0}, a1 = {0,0,0,0}, a2 = {0,0,0,0}, a3 = {0,0,0,0};
    int i = s;
    for (; i + 7 < e; i += 8) {
        int s0 = csr[i + half], s1 = csr[i + 2 + half];
        int s2 = csr[i + 4 + half], s3 = csr[i + 6 + half];
        uint2 v0 = zv[(size_t)s0 * 32 + l];
        uint2 v1 = zv[(size_t)s1 * 32 + l];
        uint2 v2 = zv[(size_t)s2 * 32 + l];
        uint2 v3 = zv[(size_t)s3 * 32 + l];
        add4h(a0, v0); add4h(a1, v1); add4h(a2, v2); add4h(a3, v3);
    }
    for (; i + 1 < e; i += 2) {
        add4h(a0, zv[(size_t)csr[i + half] * 32 + l]);
    }
    if (i < e && half == 0) {
        add4h(a0, zv[(size_t)csr[i] * 32 + l]);
    }
    a0.x += a1.x + a2.x + a3.x; a0.y += a1.y + a2.y + a3.y;
    a0.z += a1.z + a2.z + a3.z; a0.w += a1.w + a2.w + a3.w;
    a0.x += __shfl_xor(a0.x, 32, 64);
    a0.y += __shfl_xor(a0.y, 32, 64);
    a0.z += __shfl_xor(a0.z, 32, 64);
    a0.w += __shfl_xor(a0.w, 32, 64);
    float dinv = 1.f / fmaxf((float)(e - s), 1.f);
    float4 bb = ((const float4*)b2)[l];
    float4 ww = ((const float4*)W3)[half * 32 + l];
    float hx = fmaxf(a0.x * dinv + bb.x, 0.f);
    float hy = fmaxf(a0.y * dinv + bb.y, 0.f);
    float hz = fmaxf(a0.z * dinv + bb.z, 0.f);
    float hw = fmaxf(a0.w * dinv + bb.w, 0.f);
    float p = hx * ww.x + hy * ww.y + hz * ww.z + hw * ww.w;
#pragma unroll
    for (int d = 16; d > 0; d >>= 1) p += __shfl_xor(p, d, 64);
    if (l == 0) out[(size_t)n * 2 + half] = p + b3[half];
}

extern "C" void kernel_launch(void* const* d_in, const int* in_sizes, int n_in,
                              void* d_out, int out_size, void* d_ws, size_t ws_size,
                              hipStream_t stream) {
    const float* x  = (const float*)d_in[0];
    const int*   ei = (const int*)d_in[1];
    const float* W1 = (const float*)d_in[3];
    const float* b1 = (const float*)d_in[4];
    const float* W2 = (const float*)d_in[5];
    const float* b2 = (const float*)d_in[6];
    const float* W3 = (const float*)d_in[7];
    const float* b3 = (const float*)d_in[8];
    float* out = (float*)d_out;

    int N = in_sizes[0] / IN_F;   // 50000
    int E = in_sizes[1] / 2;      // 800000
    const int* row = ei;
    const int* col = ei + E;

    char* base = (char*)d_ws;
    size_t off = 0;
    auto alloc = [&](size_t bytes) -> void* {
        off = (off + 255) & ~(size_t)255;
        void* p = base + off;
        off += bytes;
        return p;
    };
    int*    deg  = (int*)alloc((size_t)2 * N * 4);   // deg + fill, one memset
    int*    fill = deg + N;
    int*    rp   = (int*)alloc((size_t)(N + 1) * 4);
    int*    tmp  = (int*)alloc((size_t)N * 4);
    int*    bsum = (int*)alloc(1024);
    int*    csr  = (int*)alloc((size_t)E * 4);
    ushort* xh   = (ushort*)alloc((size_t)N * IN_F * 2);  // x fp16; reused as z2 fp16
    float*  f2   = (float*)alloc((size_t)N * IN_F * 4);   // agg1 out fp32; reused as z2 fp32
    float*  h1   = (float*)alloc((size_t)N * HID * 4);
    ushort* w1h  = (ushort*)alloc(HID * IN_F * 2);
    ushort* w1l  = (ushort*)alloc(HID * IN_F * 2);
    ushort* w2h  = (ushort*)alloc(HID2 * HID * 2);
    ushort* w2l  = (ushort*)alloc(HID2 * HID * 2);

    hipMemsetAsync(deg, 0, (size_t)2 * N * 4, stream);
    int eb = (E + 255) / 256;
    int nb = (N + 255) / 256;   // 196
    count_deg<<<eb, 256, 0, stream>>>(col, deg, E);
    scan_block<<<nb, 256, 0, stream>>>(deg, tmp, bsum, N);
    scan_bsums<<<1, 256, 0, stream>>>(bsum, nb);
    scan_add<<<nb, 256, 0, stream>>>(tmp, bsum, rp, N);
    fill_csr<<<eb, 256, 0, stream>>>(row, col, rp, fill, csr, E);

    int t8 = N * IN_F / 8;   // 800000
    to_f16<<<(t8 + 255) / 256, 256, 0, stream>>>(x, xh, t8);
    split_weights<<<256, 256, 0, stream>>>(W1, W2, w1h, w1l, w2h, w2l);

    agg_gather<<<(N + 3) / 4, 256, 0, stream>>>(xh, rp, csr, f2, N);

    int mb = (N + 127) / 128;  // 391
    gemm_mfma<true><<<dim3(mb, HID / 128), 256, 0, stream>>>(f2, w1h, w1l, b1, h1, N, HID, IN_F);
    gemm_mfma<false><<<dim3(mb, HID2 / 128), 256, 0, stream>>>(h1, w2h, w2l, nullptr, f2, N, HID2, HID);
    to_f16<<<(t8 + 255) / 256, 256, 0, stream>>>(f2, xh, t8);   // z2 fp32 -> fp16 (xh reused)
    agg2_out<<<(N + 3) / 4, 256, 0, stream>>>(xh, rp, csr, b2, W3, b3, out, N);
}